// Round 1
// baseline (138.365 us; speedup 1.0000x reference)
//
#include <hip/hip_runtime.h>
#include <hip/hip_bf16.h>
#include <stdint.h>

typedef __bf16 bf16x8 __attribute__((ext_vector_type(8)));
typedef __bf16 bf16x4 __attribute__((ext_vector_type(4)));
typedef float  f32x4  __attribute__((ext_vector_type(4)));

static constexpr int Mdim = 2048;   // B*S
static constexpr int Ndim = 4096;   // O
static constexpr int Kdim = 4096;   // I = G*A
// alpha: [O][32][3], binary: [O][32][128][3]

// ---------------- dequant: W[o,i] = sum_b alpha[o,g,b]*binary[o,g,a,b] -> bf16 [O][K]
__global__ __launch_bounds__(256)
void bcq_dequant(const float* __restrict__ binary, const float* __restrict__ alpha,
                 __bf16* __restrict__ w) {
  long t = (long)blockIdx.x * blockDim.x + threadIdx.x;
  long e = t * 4;                       // 4 weight elements per thread
  if (e >= (long)Ndim * Kdim) return;
  int o = (int)(e >> 12);               // K = 4096
  int i = (int)(e & 4095);
  int g = i >> 7;                       // A = 128
  const float* al = alpha + ((long)o * 32 + g) * 3;
  float a0 = al[0], a1 = al[1], a2 = al[2];
  const float4* bs = (const float4*)(binary + e * 3);   // 48B, 16B-aligned
  float4 b0 = bs[0], b1 = bs[1], b2 = bs[2];
  bf16x4 wv;
  wv[0] = (__bf16)(a0 * b0.x + a1 * b0.y + a2 * b0.z);
  wv[1] = (__bf16)(a0 * b0.w + a1 * b1.x + a2 * b1.y);
  wv[2] = (__bf16)(a0 * b1.z + a1 * b1.w + a2 * b2.x);
  wv[3] = (__bf16)(a0 * b2.y + a1 * b2.z + a2 * b2.w);
  *(bf16x4*)(w + e) = wv;
}

// ---------------- f32 -> bf16 cast (vectorized 8/thread)
__global__ __launch_bounds__(256)
void cvt_bf16(const float* __restrict__ x, __bf16* __restrict__ xb, long n) {
  long t = (long)blockIdx.x * blockDim.x + threadIdx.x;
  long e = t * 8;
  if (e >= n) return;
  float4 v0 = *(const float4*)(x + e);
  float4 v1 = *(const float4*)(x + e + 4);
  bf16x8 r;
  r[0] = (__bf16)v0.x; r[1] = (__bf16)v0.y; r[2] = (__bf16)v0.z; r[3] = (__bf16)v0.w;
  r[4] = (__bf16)v1.x; r[5] = (__bf16)v1.y; r[6] = (__bf16)v1.z; r[7] = (__bf16)v1.w;
  *(bf16x8*)(xb + e) = r;
}

// ---------------- bf16 GEMM, B^T layout: C[m][n] = sum_k A[m][k]*Bw[n][k] + bias[n]
#define BM 128
#define BN 128
#define BK 32

__device__ static inline void g2l16(const void* g, void* l) {
  __builtin_amdgcn_global_load_lds(
      (const __attribute__((address_space(1))) void*)g,
      (__attribute__((address_space(3))) void*)l, 16, 0, 0);
}

__global__ __launch_bounds__(256, 2)
void gemm_bt(const __bf16* __restrict__ A, const __bf16* __restrict__ Bw,
             const float* __restrict__ bias, float* __restrict__ C) {
  __shared__ __bf16 sA[BM * BK];   // [row][k], 8 KB
  __shared__ __bf16 sB[BN * BK];   // [row][k], 8 KB
  const int tid  = threadIdx.x;
  const int lane = tid & 63;
  const int wave = tid >> 6;            // 4 waves, 2x2 wave grid (64x64 each)
  const int wm = wave >> 1, wn = wave & 1;
  const int bm = blockIdx.x & 15;       // M/BM = 16
  const int bn = blockIdx.x >> 4;       // N/BN = 32
  const int m0 = bm * BM, n0 = bn * BN;

  f32x4 acc[4][4] = {};

  const int lr = lane & 15;             // fragment row/col within 16
  const int kk = (lane >> 4) * 8;       // k-offset of this lane's 8 elements

  // staging: tile = 128x32 bf16 = 512 x 16B chunks; thread handles chunk tid and tid+256
  const int r0 = tid >> 2;              // 0..63
  const int c0 = (tid & 3) * 8;
  const __bf16* Ab = A  + (long)(m0 + r0) * Kdim + c0;
  const __bf16* Bb = Bw + (long)(n0 + r0) * Kdim + c0;

  for (int k0 = 0; k0 < Kdim; k0 += BK) {
    // LDS dest: wave-uniform base + lane*16B (hardware)
    g2l16(Ab,             sA + wave * 512);          // rows 0..63
    g2l16(Ab + 64 * Kdim, sA + 2048 + wave * 512);   // rows 64..127
    g2l16(Bb,             sB + wave * 512);
    g2l16(Bb + 64 * Kdim, sB + 2048 + wave * 512);
    Ab += BK; Bb += BK;
    __syncthreads();

    bf16x8 afrag[4], bfrag[4];
#pragma unroll
    for (int f = 0; f < 4; ++f) {
      afrag[f] = *(const bf16x8*)(sA + (wm * 64 + f * 16 + lr) * BK + kk);
      bfrag[f] = *(const bf16x8*)(sB + (wn * 64 + f * 16 + lr) * BK + kk);
    }
#pragma unroll
    for (int mf = 0; mf < 4; ++mf)
#pragma unroll
      for (int nf = 0; nf < 4; ++nf)
        acc[mf][nf] = __builtin_amdgcn_mfma_f32_16x16x32_bf16(
            afrag[mf], bfrag[nf], acc[mf][nf], 0, 0, 0);
    __syncthreads();
  }

  // epilogue: C/D layout col = lane&15, row = (lane>>4)*4 + reg  [m89-verified]
#pragma unroll
  for (int nf = 0; nf < 4; ++nf) {
    const int gcol = n0 + wn * 64 + nf * 16 + lr;
    const float bv = bias[gcol];
#pragma unroll
    for (int mf = 0; mf < 4; ++mf) {
#pragma unroll
      for (int r = 0; r < 4; ++r) {
        const int grow = m0 + wm * 64 + mf * 16 + (lane >> 4) * 4 + r;
        C[(long)grow * Ndim + gcol] = acc[mf][nf][r] + bv;
      }
    }
  }
}

extern "C" void kernel_launch(void* const* d_in, const int* in_sizes, int n_in,
                              void* d_out, int out_size, void* d_ws, size_t ws_size,
                              hipStream_t stream) {
  const float* x      = (const float*)d_in[0];   // [2,1024,4096]
  const float* binary = (const float*)d_in[1];   // [4096,32,128,3]
  const float* alpha  = (const float*)d_in[2];   // [4096,32,3]
  const float* bias   = (const float*)d_in[3];   // [4096]
  float* out = (float*)d_out;                    // [2,1024,4096] f32

  __bf16* wb = (__bf16*)d_ws;                        // 32 MB: W bf16 [N][K]
  __bf16* xb = wb + (size_t)Ndim * Kdim;             // 16 MB: X bf16 [M][K]

  // dequantize W
  {
    long n4 = (long)Ndim * Kdim / 4;
    bcq_dequant<<<(int)((n4 + 255) / 256), 256, 0, stream>>>(binary, alpha, wb);
  }
  // cast X
  {
    long n8 = (long)Mdim * Kdim / 8;
    cvt_bf16<<<(int)((n8 + 255) / 256), 256, 0, stream>>>(x, xb, (long)Mdim * Kdim);
  }
  // GEMM
  gemm_bt<<<dim3((Mdim / BM) * (Ndim / BN)), 256, 0, stream>>>(xb, wb, bias, out);
}

// Round 2
// 133.774 us; speedup vs baseline: 1.0343x; 1.0343x over previous
//
#include <hip/hip_runtime.h>
#include <hip/hip_bf16.h>
#include <stdint.h>

typedef __bf16 bf16x8 __attribute__((ext_vector_type(8)));
typedef __bf16 bf16x4 __attribute__((ext_vector_type(4)));
typedef float  f32x4  __attribute__((ext_vector_type(4)));

static constexpr int Mdim = 2048;   // B*S
static constexpr int Ndim = 4096;   // O
static constexpr int Kdim = 4096;   // I = G*A

// ---------------- dequant: W[o,i] = sum_b alpha[o,g,b]*binary[o,g,a,b] -> bf16 [O][K]
__global__ __launch_bounds__(256)
void bcq_dequant(const float* __restrict__ binary, const float* __restrict__ alpha,
                 __bf16* __restrict__ w) {
  long t = (long)blockIdx.x * blockDim.x + threadIdx.x;
  long e = t * 4;
  if (e >= (long)Ndim * Kdim) return;
  int o = (int)(e >> 12);
  int i = (int)(e & 4095);
  int g = i >> 7;
  const float* al = alpha + ((long)o * 32 + g) * 3;
  float a0 = al[0], a1 = al[1], a2 = al[2];
  const float4* bs = (const float4*)(binary + e * 3);
  float4 b0 = bs[0], b1 = bs[1], b2 = bs[2];
  bf16x4 wv;
  wv[0] = (__bf16)(a0 * b0.x + a1 * b0.y + a2 * b0.z);
  wv[1] = (__bf16)(a0 * b0.w + a1 * b1.x + a2 * b1.y);
  wv[2] = (__bf16)(a0 * b1.z + a1 * b1.w + a2 * b2.x);
  wv[3] = (__bf16)(a0 * b2.y + a1 * b2.z + a2 * b2.w);
  *(bf16x4*)(w + e) = wv;
}

// ---------------- f32 -> bf16 cast
__global__ __launch_bounds__(256)
void cvt_bf16(const float* __restrict__ x, __bf16* __restrict__ xb, long n) {
  long t = (long)blockIdx.x * blockDim.x + threadIdx.x;
  long e = t * 8;
  if (e >= n) return;
  float4 v0 = *(const float4*)(x + e);
  float4 v1 = *(const float4*)(x + e + 4);
  bf16x8 r;
  r[0] = (__bf16)v0.x; r[1] = (__bf16)v0.y; r[2] = (__bf16)v0.z; r[3] = (__bf16)v0.w;
  r[4] = (__bf16)v1.x; r[5] = (__bf16)v1.y; r[6] = (__bf16)v1.z; r[7] = (__bf16)v1.w;
  *(bf16x8*)(xb + e) = r;
}

// ---------------- split-K reduce: out = P0 + P1 + bias
__global__ __launch_bounds__(256)
void reduce_add(const float* __restrict__ p0, const float* __restrict__ p1,
                const float* __restrict__ bias, float* __restrict__ out) {
  long e = ((long)blockIdx.x * 256 + threadIdx.x) * 4;
  if (e >= (long)Mdim * Ndim) return;
  float4 a = *(const float4*)(p0 + e);
  float4 b = *(const float4*)(p1 + e);
  int col = (int)(e & (Ndim - 1));
  float4 bv = *(const float4*)(bias + col);
  float4 r;
  r.x = a.x + b.x + bv.x; r.y = a.y + b.y + bv.y;
  r.z = a.z + b.z + bv.z; r.w = a.w + b.w + bv.w;
  *(float4*)(out + e) = r;
}

// ---------------- 256x256 8-phase split-K GEMM (bf16 MFMA), B^T layout
static constexpr int BK = 64;
static constexpr int KSLICE = 2048;
static constexpr int NT = KSLICE / BK;   // 32 K-tiles per slice
static constexpr int ITERS = NT / 2;     // 16

__device__ __forceinline__ void g2l16(const void* g, void* l) {
  __builtin_amdgcn_global_load_lds(
      (const __attribute__((address_space(1))) void*)g,
      (__attribute__((address_space(3))) void*)l, 16, 0, 0);
}

#define BAR()    __builtin_amdgcn_s_barrier()
#define LGKM0()  asm volatile("s_waitcnt lgkmcnt(0)" ::: "memory")
#define SCHED0() __builtin_amdgcn_sched_barrier(0)

// stage: LDS linear dest (wave-uniform base + lane*16); source pre-swizzled so that
// read-side XOR swizzle (granule ^= row&7) sees data in place.  [rule 21]
#define STAGE_A(t, H, b) do { \
  _Pragma("unroll") for (int j_ = 0; j_ < 2; ++j_) \
    g2l16(baseA[j_] + (H) * 128 * Kdim + (t) * 64, \
          sm + (b) * 65536 + (H) * 16384 + (w * 2 + j_) * 1024); \
} while (0)
#define STAGE_B(t, H, b) do { \
  _Pragma("unroll") for (int j_ = 0; j_ < 2; ++j_) \
    g2l16(baseB[j_] + (H) * 128 * Kdim + (t) * 64, \
          sm + (b) * 65536 + 32768 + (H) * 16384 + (w * 2 + j_) * 1024); \
} while (0)

#define LOAD_A4(dst, b, m0_) do { \
  _Pragma("unroll") for (int m_ = 0; m_ < 4; ++m_) \
    _Pragma("unroll") for (int h_ = 0; h_ < 2; ++h_) \
      dst[m_][h_] = *(const bf16x8*)(sm + (b) * 65536 + aoffbase + ((m0_) + m_) * 2048 + swz[h_]); \
} while (0)
#define LOAD_B2(dst, b, n0_) do { \
  _Pragma("unroll") for (int n_ = 0; n_ < 2; ++n_) \
    _Pragma("unroll") for (int h_ = 0; h_ < 2; ++h_) \
      dst[n_][h_] = *(const bf16x8*)(sm + (b) * 65536 + boffbase + ((n0_) + n_) * 2048 + swz[h_]); \
} while (0)

#define MMA8(fa_, fb_, m0_, n0_) do { \
  __builtin_amdgcn_s_setprio(1); \
  _Pragma("unroll") for (int m_ = 0; m_ < 4; ++m_) \
    _Pragma("unroll") for (int n_ = 0; n_ < 2; ++n_) { \
      acc[(m0_) + m_][(n0_) + n_] = __builtin_amdgcn_mfma_f32_16x16x32_bf16( \
          fa_[m_][0], fb_[n_][0], acc[(m0_) + m_][(n0_) + n_], 0, 0, 0); \
      acc[(m0_) + m_][(n0_) + n_] = __builtin_amdgcn_mfma_f32_16x16x32_bf16( \
          fa_[m_][1], fb_[n_][1], acc[(m0_) + m_][(n0_) + n_], 0, 0, 0); \
    } \
  __builtin_amdgcn_s_setprio(0); \
} while (0)

__global__ __launch_bounds__(512, 2)
void gemm8(const __bf16* __restrict__ A, const __bf16* __restrict__ Bw,
           float* __restrict__ P) {
  __shared__ __align__(128) char sm[131072];   // 2 bufs x (A 32KB + B 32KB)
  const int tid = threadIdx.x, lane = tid & 63, w = tid >> 6;
  const int wm = w >> 2, wn = w & 3;           // wave grid 2M x 4N, per-wave 128x64

  // XCD-aware bijective swizzle (256 = 8 XCD x 32)
  const int bid = blockIdx.x;
  const int logical = (bid & 7) * 32 + (bid >> 3);
  const int ks = logical >> 7;                 // split-K slice 0/1
  const int tile = logical & 127;
  const int tm = tile & 7, tn = tile >> 3;     // 8 x 16 tiles
  const int kbase = ks * KSLICE;

  float* Pout = P + (long)ks * Mdim * Ndim;

  // staging per-lane source bases (pre-swizzled granule)
  const int rlo = lane >> 3;
  const int gsw = (lane & 7) ^ rlo;            // inverse-swizzle granule
  const __bf16* baseA[2];
  const __bf16* baseB[2];
#pragma unroll
  for (int j = 0; j < 2; ++j) {
    int rp = (w * 2 + j) * 8 + rlo;            // row within 128-row half
    baseA[j] = A  + (long)(tm * 256 + rp) * Kdim + kbase + gsw * 8;
    baseB[j] = Bw + (long)(tn * 256 + rp) * Kdim + kbase + gsw * 8;
  }

  // read-side swizzled offsets
  int swz[2];
#pragma unroll
  for (int h = 0; h < 2; ++h)
    swz[h] = (((h * 4 + (lane >> 4)) ^ (lane & 7)) << 4);
  const int aoffbase = (wm * 128 + (lane & 15)) * 128;
  const int boffbase = 32768 + (wn * 64 + (lane & 15)) * 128;

  f32x4 acc[8][4] = {};

  // prologue: tile0 fully + B halves of tile1; leave 4 loads in flight
  STAGE_A(0, 0, 0); STAGE_A(0, 1, 0); STAGE_B(0, 0, 0); STAGE_B(0, 1, 0);
  STAGE_B(1, 0, 1); STAGE_B(1, 1, 1);
  asm volatile("s_waitcnt vmcnt(4)" ::: "memory");
  BAR();

  bf16x8 fa[4][2], fb01[2][2], fb23[2][2];

  for (int i = 0; i < ITERS; ++i) {
    const int t0 = 2 * i, t1 = 2 * i + 1;
    const bool pf = (i < ITERS - 1);
    // P1: read A m0-3 + B n0-1 (buf0); stage A-lo(t1)->buf1
    LOAD_A4(fa, 0, 0); LOAD_B2(fb01, 0, 0);
    STAGE_A(t1, 0, 1);
    BAR(); LGKM0(); SCHED0();
    MMA8(fa, fb01, 0, 0);
    BAR();
    // P2: read B n2-3; stage A-hi(t1)->buf1
    LOAD_B2(fb23, 0, 2);
    STAGE_A(t1, 1, 1);
    BAR(); LGKM0(); SCHED0();
    MMA8(fa, fb23, 0, 2);
    BAR();
    // P3: read A m4-7; stage B-lo(t0+2)->buf0 (B buf0 fully read after P2)
    LOAD_A4(fa, 0, 4);
    if (pf) STAGE_B(t0 + 2, 0, 0);
    BAR(); LGKM0(); SCHED0();
    MMA8(fa, fb01, 4, 0);
    BAR();
    // P4: stage B-hi(t0+2); counted vmcnt -> tile t1 fully resident
    if (pf) STAGE_B(t0 + 2, 1, 0);
    if (i == ITERS - 1) { asm volatile("s_waitcnt vmcnt(0)" ::: "memory"); }
    else                { asm volatile("s_waitcnt vmcnt(4)" ::: "memory"); }
    BAR();
    MMA8(fa, fb23, 4, 2);
    BAR();
    // P5: read A m0-3 + B n0-1 (buf1); stage A-lo(t0+2)->buf0 (A buf0 read done P3)
    LOAD_A4(fa, 1, 0); LOAD_B2(fb01, 1, 0);
    if (pf) STAGE_A(t0 + 2, 0, 0);
    BAR(); LGKM0(); SCHED0();
    MMA8(fa, fb01, 0, 0);
    BAR();
    // P6: read B n2-3 (buf1); stage A-hi(t0+2)->buf0
    LOAD_B2(fb23, 1, 2);
    if (pf) STAGE_A(t0 + 2, 1, 0);
    BAR(); LGKM0(); SCHED0();
    MMA8(fa, fb23, 0, 2);
    BAR();
    // P7: read A m4-7 (buf1); stage B-lo(t1+2)->buf1 (B buf1 read done P6)
    LOAD_A4(fa, 1, 4);
    if (pf) STAGE_B(t1 + 2, 0, 1);
    BAR(); LGKM0(); SCHED0();
    MMA8(fa, fb01, 4, 0);
    BAR();
    // P8: stage B-hi(t1+2); counted vmcnt -> tile t0+2 fully resident
    if (pf) STAGE_B(t1 + 2, 1, 1);
    asm volatile("s_waitcnt vmcnt(4)" ::: "memory");
    BAR();
    MMA8(fa, fb23, 4, 2);
    BAR();
  }

  // epilogue: C/D layout col=lane&15, row=(lane>>4)*4+reg
  const int r4 = (lane >> 4) * 4;
  const int cl = lane & 15;
#pragma unroll
  for (int m = 0; m < 8; ++m)
#pragma unroll
    for (int n = 0; n < 4; ++n)
#pragma unroll
      for (int r = 0; r < 4; ++r) {
        int row = tm * 256 + wm * 128 + m * 16 + r4 + r;
        int col = tn * 256 + wn * 64 + n * 16 + cl;
        Pout[(long)row * Ndim + col] = acc[m][n][r];
      }
}

extern "C" void kernel_launch(void* const* d_in, const int* in_sizes, int n_in,
                              void* d_out, int out_size, void* d_ws, size_t ws_size,
                              hipStream_t stream) {
  const float* x      = (const float*)d_in[0];
  const float* binary = (const float*)d_in[1];
  const float* alpha  = (const float*)d_in[2];
  const float* bias   = (const float*)d_in[3];
  float* out = (float*)d_out;

  __bf16* wb = (__bf16*)d_ws;                              // 32 MB  W bf16 [N][K]
  __bf16* xb = wb + (size_t)Ndim * Kdim;                   // 16 MB  X bf16 [M][K]
  float*  pp = (float*)(xb + (size_t)Mdim * Kdim);         // 64 MB  partials [2][M][N]

  {
    long n4 = (long)Ndim * Kdim / 4;
    bcq_dequant<<<(int)((n4 + 255) / 256), 256, 0, stream>>>(binary, alpha, wb);
  }
  {
    long n8 = (long)Mdim * Kdim / 8;
    cvt_bf16<<<(int)((n8 + 255) / 256), 256, 0, stream>>>(x, xb, (long)Mdim * Kdim);
  }
  gemm8<<<dim3(256), 512, 0, stream>>>(xb, wb, pp);
  {
    long n4 = (long)Mdim * Ndim / 4;
    reduce_add<<<(int)((n4 + 255) / 256), 256, 0, stream>>>(
        pp, pp + (size_t)Mdim * Ndim, bias, out);
  }
}

// Round 3
// 123.347 us; speedup vs baseline: 1.1218x; 1.0845x over previous
//
#include <hip/hip_runtime.h>
#include <hip/hip_bf16.h>
#include <stdint.h>

typedef __bf16 bf16x8 __attribute__((ext_vector_type(8)));
typedef __bf16 bf16x4 __attribute__((ext_vector_type(4)));
typedef float  f32x4  __attribute__((ext_vector_type(4)));

static constexpr int Mdim = 2048;   // B*S
static constexpr int Ndim = 4096;   // O
static constexpr int Kdim = 4096;   // I = G*A
static constexpr int DQ_BLOCKS = (Ndim * Kdim / 4) / 256;        // 16384
static constexpr int CVT_BLOCKS = (Mdim * Kdim / 8) / 256;       // 4096

// ---------------- fused prep: dequant W -> bf16 [O][K], cast X -> bf16 [M][K]
__global__ __launch_bounds__(256)
void prep(const float* __restrict__ binary, const float* __restrict__ alpha,
          const float* __restrict__ x, __bf16* __restrict__ w,
          __bf16* __restrict__ xb) {
  const int b = blockIdx.x;
  if (b < DQ_BLOCKS) {
    long e = ((long)b * 256 + threadIdx.x) * 4;
    int o = (int)(e >> 12);
    int i = (int)(e & 4095);
    int g = i >> 7;
    const float* al = alpha + ((long)o * 32 + g) * 3;
    float a0 = al[0], a1 = al[1], a2 = al[2];
    const float4* bs = (const float4*)(binary + e * 3);
    float4 b0 = bs[0], b1 = bs[1], b2 = bs[2];
    bf16x4 wv;
    wv[0] = (__bf16)(a0 * b0.x + a1 * b0.y + a2 * b0.z);
    wv[1] = (__bf16)(a0 * b0.w + a1 * b1.x + a2 * b1.y);
    wv[2] = (__bf16)(a0 * b1.z + a1 * b1.w + a2 * b2.x);
    wv[3] = (__bf16)(a0 * b2.y + a1 * b2.z + a2 * b2.w);
    *(bf16x4*)(w + e) = wv;
  } else {
    long e = ((long)(b - DQ_BLOCKS) * 256 + threadIdx.x) * 8;
    float4 v0 = *(const float4*)(x + e);
    float4 v1 = *(const float4*)(x + e + 4);
    bf16x8 r;
    r[0] = (__bf16)v0.x; r[1] = (__bf16)v0.y; r[2] = (__bf16)v0.z; r[3] = (__bf16)v0.w;
    r[4] = (__bf16)v1.x; r[5] = (__bf16)v1.y; r[6] = (__bf16)v1.z; r[7] = (__bf16)v1.w;
    *(bf16x8*)(xb + e) = r;
  }
}

// ---------------- split-K reduce: out = P0 + P1 + bias  (bf16 partials)
__global__ __launch_bounds__(256)
void reduce_add(const __bf16* __restrict__ p, const float* __restrict__ bias,
                float* __restrict__ out) {
  long e = ((long)blockIdx.x * 256 + threadIdx.x) * 8;
  bf16x8 a = *(const bf16x8*)(p + e);
  bf16x8 c = *(const bf16x8*)(p + (long)Mdim * Ndim + e);
  int col = (int)(e & (Ndim - 1));
  float4 bv0 = *(const float4*)(bias + col);
  float4 bv1 = *(const float4*)(bias + col + 4);
  float4 r0, r1;
  r0.x = (float)a[0] + (float)c[0] + bv0.x;
  r0.y = (float)a[1] + (float)c[1] + bv0.y;
  r0.z = (float)a[2] + (float)c[2] + bv0.z;
  r0.w = (float)a[3] + (float)c[3] + bv0.w;
  r1.x = (float)a[4] + (float)c[4] + bv1.x;
  r1.y = (float)a[5] + (float)c[5] + bv1.y;
  r1.z = (float)a[6] + (float)c[6] + bv1.z;
  r1.w = (float)a[7] + (float)c[7] + bv1.w;
  *(float4*)(out + e) = r0;
  *(float4*)(out + e + 4) = r1;
}

// ---------------- 256x256 8-phase split-K GEMM (bf16 MFMA), B^T layout
static constexpr int BK = 64;
static constexpr int KSLICE = 2048;
static constexpr int NT = KSLICE / BK;   // 32 K-tiles per slice
static constexpr int ITERS = NT / 2;     // 16

__device__ __forceinline__ void g2l16(const void* g, void* l) {
  __builtin_amdgcn_global_load_lds(
      (const __attribute__((address_space(1))) void*)g,
      (__attribute__((address_space(3))) void*)l, 16, 0, 0);
}

#define BAR()    __builtin_amdgcn_s_barrier()
#define LGKM0()  asm volatile("s_waitcnt lgkmcnt(0)" ::: "memory")
#define SCHED0() __builtin_amdgcn_sched_barrier(0)

#define STAGE_A(t, H, b) do { \
  _Pragma("unroll") for (int j_ = 0; j_ < 2; ++j_) \
    g2l16(baseA[j_] + (H) * 128 * Kdim + (t) * 64, \
          sm + (b) * 65536 + (H) * 16384 + (w * 2 + j_) * 1024); \
} while (0)
#define STAGE_B(t, H, b) do { \
  _Pragma("unroll") for (int j_ = 0; j_ < 2; ++j_) \
    g2l16(baseB[j_] + (H) * 128 * Kdim + (t) * 64, \
          sm + (b) * 65536 + 32768 + (H) * 16384 + (w * 2 + j_) * 1024); \
} while (0)

#define LOAD_A4(dst, b, m0_) do { \
  _Pragma("unroll") for (int m_ = 0; m_ < 4; ++m_) \
    _Pragma("unroll") for (int h_ = 0; h_ < 2; ++h_) \
      dst[m_][h_] = *(const bf16x8*)(sm + (b) * 65536 + aoffbase + ((m0_) + m_) * 2048 + swz[h_]); \
} while (0)
#define LOAD_B2(dst, b, n0_) do { \
  _Pragma("unroll") for (int n_ = 0; n_ < 2; ++n_) \
    _Pragma("unroll") for (int h_ = 0; h_ < 2; ++h_) \
      dst[n_][h_] = *(const bf16x8*)(sm + (b) * 65536 + boffbase + ((n0_) + n_) * 2048 + swz[h_]); \
} while (0)

#define MMA8(fa_, fb_, m0_, n0_) do { \
  __builtin_amdgcn_s_setprio(1); \
  _Pragma("unroll") for (int m_ = 0; m_ < 4; ++m_) \
    _Pragma("unroll") for (int n_ = 0; n_ < 2; ++n_) { \
      acc[(m0_) + m_][(n0_) + n_] = __builtin_amdgcn_mfma_f32_16x16x32_bf16( \
          fa_[m_][0], fb_[n_][0], acc[(m0_) + m_][(n0_) + n_], 0, 0, 0); \
      acc[(m0_) + m_][(n0_) + n_] = __builtin_amdgcn_mfma_f32_16x16x32_bf16( \
          fa_[m_][1], fb_[n_][1], acc[(m0_) + m_][(n0_) + n_], 0, 0, 0); \
    } \
  __builtin_amdgcn_s_setprio(0); \
} while (0)

__global__ __launch_bounds__(512, 2)
void gemm8(const __bf16* __restrict__ A, const __bf16* __restrict__ Bw,
           __bf16* __restrict__ P) {
  __shared__ __align__(128) char sm[131072];   // 2 bufs x (A 32KB + B 32KB)
  const int tid = threadIdx.x, lane = tid & 63, w = tid >> 6;
  const int wm = w >> 2, wn = w & 3;           // wave grid 2M x 4N, per-wave 128x64

  // XCD-aware bijective swizzle (256 = 8 XCD x 32)
  const int bid = blockIdx.x;
  const int logical = (bid & 7) * 32 + (bid >> 3);
  const int ks = logical >> 7;                 // split-K slice 0/1
  const int tile = logical & 127;
  const int tm = tile & 7, tn = tile >> 3;     // 8 x 16 tiles
  const int kbase = ks * KSLICE;

  __bf16* Pout = P + (long)ks * Mdim * Ndim;

  // staging per-lane source bases (pre-swizzled granule)
  const int rlo = lane >> 3;
  const int gsw = (lane & 7) ^ rlo;            // inverse-swizzle granule
  const __bf16* baseA[2];
  const __bf16* baseB[2];
#pragma unroll
  for (int j = 0; j < 2; ++j) {
    int rp = (w * 2 + j) * 8 + rlo;            // row within 128-row half
    baseA[j] = A  + (long)(tm * 256 + rp) * Kdim + kbase + gsw * 8;
    baseB[j] = Bw + (long)(tn * 256 + rp) * Kdim + kbase + gsw * 8;
  }

  // read-side swizzled offsets
  int swz[2];
#pragma unroll
  for (int h = 0; h < 2; ++h)
    swz[h] = (((h * 4 + (lane >> 4)) ^ (lane & 7)) << 4);
  const int aoffbase = (wm * 128 + (lane & 15)) * 128;
  const int boffbase = 32768 + (wn * 64 + (lane & 15)) * 128;

  f32x4 acc[8][4] = {};

  // prologue: tile0 fully + B halves of tile1; leave 4 loads in flight
  STAGE_A(0, 0, 0); STAGE_A(0, 1, 0); STAGE_B(0, 0, 0); STAGE_B(0, 1, 0);
  STAGE_B(1, 0, 1); STAGE_B(1, 1, 1);
  asm volatile("s_waitcnt vmcnt(4)" ::: "memory");
  BAR();

  bf16x8 fa[4][2], fb01[2][2], fb23[2][2];

  for (int i = 0; i < ITERS; ++i) {
    const int t0 = 2 * i, t1 = 2 * i + 1;
    const bool pf = (i < ITERS - 1);
    // P1: read A m0-3 + B n0-1 (buf0); stage A-lo(t1)->buf1
    LOAD_A4(fa, 0, 0); LOAD_B2(fb01, 0, 0);
    STAGE_A(t1, 0, 1);
    BAR(); LGKM0(); SCHED0();
    MMA8(fa, fb01, 0, 0);
    BAR();
    // P2: read B n2-3; stage A-hi(t1)->buf1
    LOAD_B2(fb23, 0, 2);
    STAGE_A(t1, 1, 1);
    BAR(); LGKM0(); SCHED0();
    MMA8(fa, fb23, 0, 2);
    BAR();
    // P3: read A m4-7; stage B-lo(t0+2)->buf0
    LOAD_A4(fa, 0, 4);
    if (pf) STAGE_B(t0 + 2, 0, 0);
    BAR(); LGKM0(); SCHED0();
    MMA8(fa, fb01, 4, 0);
    BAR();
    // P4: stage B-hi(t0+2); counted vmcnt -> tile t1 fully resident
    if (pf) STAGE_B(t0 + 2, 1, 0);
    if (i == ITERS - 1) { asm volatile("s_waitcnt vmcnt(0)" ::: "memory"); }
    else                { asm volatile("s_waitcnt vmcnt(4)" ::: "memory"); }
    BAR();
    MMA8(fa, fb23, 4, 2);
    BAR();
    // P5: read A m0-3 + B n0-1 (buf1); stage A-lo(t0+2)->buf0
    LOAD_A4(fa, 1, 0); LOAD_B2(fb01, 1, 0);
    if (pf) STAGE_A(t0 + 2, 0, 0);
    BAR(); LGKM0(); SCHED0();
    MMA8(fa, fb01, 0, 0);
    BAR();
    // P6: read B n2-3 (buf1); stage A-hi(t0+2)->buf0
    LOAD_B2(fb23, 1, 2);
    if (pf) STAGE_A(t0 + 2, 1, 0);
    BAR(); LGKM0(); SCHED0();
    MMA8(fa, fb23, 0, 2);
    BAR();
    // P7: read A m4-7 (buf1); stage B-lo(t1+2)->buf1
    LOAD_A4(fa, 1, 4);
    if (pf) STAGE_B(t1 + 2, 0, 1);
    BAR(); LGKM0(); SCHED0();
    MMA8(fa, fb01, 4, 0);
    BAR();
    // P8: stage B-hi(t1+2); counted vmcnt -> tile t0+2 fully resident
    if (pf) STAGE_B(t1 + 2, 1, 1);
    asm volatile("s_waitcnt vmcnt(4)" ::: "memory");
    BAR();
    MMA8(fa, fb23, 4, 2);
    BAR();
  }

  // epilogue: C/D layout col=lane&15, row=(lane>>4)*4+reg ; bf16 partials
  const int r4 = (lane >> 4) * 4;
  const int cl = lane & 15;
#pragma unroll
  for (int m = 0; m < 8; ++m)
#pragma unroll
    for (int n = 0; n < 4; ++n)
#pragma unroll
      for (int r = 0; r < 4; ++r) {
        int row = tm * 256 + wm * 128 + m * 16 + r4 + r;
        int col = tn * 256 + wn * 64 + n * 16 + cl;
        Pout[(long)row * Ndim + col] = (__bf16)acc[m][n][r];
      }
}

extern "C" void kernel_launch(void* const* d_in, const int* in_sizes, int n_in,
                              void* d_out, int out_size, void* d_ws, size_t ws_size,
                              hipStream_t stream) {
  const float* x      = (const float*)d_in[0];
  const float* binary = (const float*)d_in[1];
  const float* alpha  = (const float*)d_in[2];
  const float* bias   = (const float*)d_in[3];
  float* out = (float*)d_out;

  __bf16* wb = (__bf16*)d_ws;                              // 32 MB  W bf16 [N][K]
  __bf16* xb = wb + (size_t)Ndim * Kdim;                   // 16 MB  X bf16 [M][K]
  __bf16* pp = xb + (size_t)Mdim * Kdim;                   // 32 MB  partials bf16 [2][M][N]

  prep<<<dim3(DQ_BLOCKS + CVT_BLOCKS), 256, 0, stream>>>(binary, alpha, x, wb, xb);
  gemm8<<<dim3(256), 512, 0, stream>>>(xb, wb, pp);
  reduce_add<<<dim3(Mdim * Ndim / 8 / 256), 256, 0, stream>>>(pp, bias, out);
}

// Round 4
// 122.772 us; speedup vs baseline: 1.1270x; 1.0047x over previous
//
#include <hip/hip_runtime.h>
#include <hip/hip_bf16.h>
#include <stdint.h>

typedef __bf16 bf16x8 __attribute__((ext_vector_type(8)));
typedef __bf16 bf16x4 __attribute__((ext_vector_type(4)));
typedef float  f32x4  __attribute__((ext_vector_type(4)));

static constexpr int Mdim = 2048;   // B*S
static constexpr int Ndim = 4096;   // O
static constexpr int Kdim = 4096;   // I = G*A
static constexpr int DQ_BLOCKS = (Ndim * Kdim / 4) / 256;        // 16384
static constexpr int CVT_BLOCKS = (Mdim * Kdim / 8) / 256;       // 4096

// ---------------- fused prep: dequant W -> bf16 [O][K], cast X -> bf16 [M][K]
__global__ __launch_bounds__(256)
void prep(const float* __restrict__ binary, const float* __restrict__ alpha,
          const float* __restrict__ x, __bf16* __restrict__ w,
          __bf16* __restrict__ xb) {
  const int b = blockIdx.x;
  if (b < DQ_BLOCKS) {
    long e = ((long)b * 256 + threadIdx.x) * 4;
    int o = (int)(e >> 12);
    int i = (int)(e & 4095);
    int g = i >> 7;
    const float* al = alpha + ((long)o * 32 + g) * 3;
    float a0 = al[0], a1 = al[1], a2 = al[2];
    const float4* bs = (const float4*)(binary + e * 3);
    float4 b0 = bs[0], b1 = bs[1], b2 = bs[2];
    bf16x4 wv;
    wv[0] = (__bf16)(a0 * b0.x + a1 * b0.y + a2 * b0.z);
    wv[1] = (__bf16)(a0 * b0.w + a1 * b1.x + a2 * b1.y);
    wv[2] = (__bf16)(a0 * b1.z + a1 * b1.w + a2 * b2.x);
    wv[3] = (__bf16)(a0 * b2.y + a1 * b2.z + a2 * b2.w);
    *(bf16x4*)(w + e) = wv;
  } else {
    long e = ((long)(b - DQ_BLOCKS) * 256 + threadIdx.x) * 8;
    float4 v0 = *(const float4*)(x + e);
    float4 v1 = *(const float4*)(x + e + 4);
    bf16x8 r;
    r[0] = (__bf16)v0.x; r[1] = (__bf16)v0.y; r[2] = (__bf16)v0.z; r[3] = (__bf16)v0.w;
    r[4] = (__bf16)v1.x; r[5] = (__bf16)v1.y; r[6] = (__bf16)v1.z; r[7] = (__bf16)v1.w;
    *(bf16x8*)(xb + e) = r;
  }
}

// ---------------- 256x128-tile bf16 GEMM, no split-K, triple-buffered LDS,
// counted vmcnt(6) steady state.  C[m][n] = sum_k A[m][k]*Bw[n][k] + bias[n]
static constexpr int NT = Kdim / 64;     // 64 K-tiles
static constexpr int BUF = 49152;        // 32KB A + 16KB B per buffer

__device__ __forceinline__ void g2l16(const void* g, void* l) {
  __builtin_amdgcn_global_load_lds(
      (const __attribute__((address_space(1))) void*)g,
      (__attribute__((address_space(3))) void*)l, 16, 0, 0);
}

#define BAR()    __builtin_amdgcn_s_barrier()
#define LGKM0()  asm volatile("s_waitcnt lgkmcnt(0)" ::: "memory")
#define SCHED0() __builtin_amdgcn_sched_barrier(0)
#define VMC6()   asm volatile("s_waitcnt vmcnt(6)" ::: "memory")
#define VMC0()   asm volatile("s_waitcnt vmcnt(0)" ::: "memory")

// stage: LDS linear dest (wave-uniform base + lane*16); global source pre-swizzled
// (granule ^= row&7) so the read-side XOR sees data in place.  [rule 21]
#define STAGE_A(t, H, bo) do { \
  _Pragma("unroll") for (int j_ = 0; j_ < 2; ++j_) \
    g2l16(baseA[j_] + (H) * 128 * (long)Kdim + (t) * 64, \
          sm + (bo) + (H) * 16384 + (w * 2 + j_) * 1024); \
} while (0)
#define STAGE_B(t, bo) do { \
  _Pragma("unroll") for (int j_ = 0; j_ < 2; ++j_) \
    g2l16(baseB[j_] + (t) * 64, \
          sm + (bo) + 32768 + (w * 2 + j_) * 1024); \
} while (0)

#define LOAD_A4(dst, bo, m0_) do { \
  _Pragma("unroll") for (int m_ = 0; m_ < 4; ++m_) \
    _Pragma("unroll") for (int h_ = 0; h_ < 2; ++h_) \
      dst[m_][h_] = *(const bf16x8*)(sm + (bo) + aoffbase + ((m0_) + m_) * 2048 + swz[h_]); \
} while (0)
#define LOAD_B2(dst, bo) do { \
  _Pragma("unroll") for (int n_ = 0; n_ < 2; ++n_) \
    _Pragma("unroll") for (int h_ = 0; h_ < 2; ++h_) \
      dst[n_][h_] = *(const bf16x8*)(sm + (bo) + boffbase + n_ * 2048 + swz[h_]); \
} while (0)

#define MMA16(fa_, fb_, m0_) do { \
  __builtin_amdgcn_s_setprio(1); \
  _Pragma("unroll") for (int m_ = 0; m_ < 4; ++m_) \
    _Pragma("unroll") for (int n_ = 0; n_ < 2; ++n_) { \
      acc[(m0_) + m_][n_] = __builtin_amdgcn_mfma_f32_16x16x32_bf16( \
          fa_[m_][0], fb_[n_][0], acc[(m0_) + m_][n_], 0, 0, 0); \
      acc[(m0_) + m_][n_] = __builtin_amdgcn_mfma_f32_16x16x32_bf16( \
          fa_[m_][1], fb_[n_][1], acc[(m0_) + m_][n_], 0, 0, 0); \
    } \
  __builtin_amdgcn_s_setprio(0); \
} while (0)

__global__ __launch_bounds__(512, 2)
void gemm3(const __bf16* __restrict__ A, const __bf16* __restrict__ Bw,
           const float* __restrict__ bias, float* __restrict__ out) {
  __shared__ __align__(128) char sm[3 * BUF];   // 144 KB
  const int tid = threadIdx.x, lane = tid & 63, w = tid >> 6;
  const int wm = w >> 2, wn = w & 3;            // 2M x 4N waves; per-wave 128x32

  // XCD-aware bijective swizzle (256 blocks = 8 XCD x 32)
  const int bid = blockIdx.x;
  const int logical = (bid & 7) * 32 + (bid >> 3);
  const int tm = logical & 7;                   // 8 M-tiles
  const int tn = logical >> 3;                  // 32 N-tiles

  // staging per-lane source bases (pre-swizzled granule)
  const int rlo = lane >> 3;
  const int gsw = (lane & 7) ^ rlo;             // inverse-swizzle granule
  const __bf16* baseA[2];
  const __bf16* baseB[2];
#pragma unroll
  for (int j = 0; j < 2; ++j) {
    int rp = (w * 2 + j) * 8 + rlo;             // 0..127
    baseA[j] = A  + (long)(tm * 256 + rp) * Kdim + gsw * 8;   // rows 0..127 of half
    baseB[j] = Bw + (long)(tn * 128 + rp) * Kdim + gsw * 8;   // rows 0..127
  }

  // read-side swizzled offsets
  int swz[2];
#pragma unroll
  for (int h = 0; h < 2; ++h)
    swz[h] = (((h * 4 + (lane >> 4)) ^ (lane & 7)) << 4);
  const int aoffbase = (wm * 128 + (lane & 15)) * 128;
  const int boffbase = 32768 + (wn * 32 + (lane & 15)) * 128;

  f32x4 acc[8][2] = {};

  // prologue: stage tile0 -> buf0, tile1 -> buf1; wait tile0 (keep tile1's 6 in flight)
  STAGE_A(0, 0, 0);     STAGE_A(0, 1, 0);     STAGE_B(0, 0);
  STAGE_A(1, 0, BUF);   STAGE_A(1, 1, BUF);   STAGE_B(1, BUF);
  VMC6();
  BAR();

  bf16x8 fa[4][2], fa2[4][2], fb[2][2];
  int ba = 0, bb = BUF, bc = 2 * BUF;           // read-buf, next-buf, stage-buf

  for (int t = 0; t < NT; ++t) {
    const bool pf = (t + 2 < NT);
    // P1: read A m0-3 + B (buf ba); stage A(t+2)-lo -> bc
    LOAD_A4(fa, ba, 0);
    LOAD_B2(fb, ba);
    if (pf) STAGE_A(t + 2, 0, bc);
    BAR(); LGKM0(); SCHED0();
    MMA16(fa, fb, 0);
    BAR();
    // P2: read A m4-7; stage A(t+2)-hi + B(t+2) -> bc; counted wait -> tile t+1 resident
    LOAD_A4(fa2, ba, 4);
    if (pf) { STAGE_A(t + 2, 1, bc); STAGE_B(t + 2, bc); }
    if (t < NT - 2) { VMC6(); } else { VMC0(); }
    BAR(); LGKM0(); SCHED0();
    MMA16(fa2, fb, 4);
    BAR();
    // rotate buffers
    int tmp = ba; ba = bb; bb = bc; bc = tmp;
  }

  // epilogue: C/D layout col=lane&15, row=(lane>>4)*4+reg ; fuse bias, f32 out
  const int r4 = (lane >> 4) * 4;
  const int cl = lane & 15;
#pragma unroll
  for (int n = 0; n < 2; ++n) {
    const int col = tn * 128 + wn * 32 + n * 16 + cl;
    const float bv = bias[col];
#pragma unroll
    for (int m = 0; m < 8; ++m)
#pragma unroll
      for (int r = 0; r < 4; ++r) {
        const int row = tm * 256 + wm * 128 + m * 16 + r4 + r;
        out[(long)row * Ndim + col] = acc[m][n][r] + bv;
      }
  }
}

extern "C" void kernel_launch(void* const* d_in, const int* in_sizes, int n_in,
                              void* d_out, int out_size, void* d_ws, size_t ws_size,
                              hipStream_t stream) {
  const float* x      = (const float*)d_in[0];
  const float* binary = (const float*)d_in[1];
  const float* alpha  = (const float*)d_in[2];
  const float* bias   = (const float*)d_in[3];
  float* out = (float*)d_out;

  __bf16* wb = (__bf16*)d_ws;                              // 32 MB  W bf16 [N][K]
  __bf16* xb = wb + (size_t)Ndim * Kdim;                   // 16 MB  X bf16 [M][K]

  prep<<<dim3(DQ_BLOCKS + CVT_BLOCKS), 256, 0, stream>>>(binary, alpha, x, wb, xb);
  gemm3<<<dim3(256), 512, 0, stream>>>(xb, wb, bias, out);
}

// Round 5
// 120.736 us; speedup vs baseline: 1.1460x; 1.0169x over previous
//
#include <hip/hip_runtime.h>
#include <hip/hip_bf16.h>
#include <stdint.h>

typedef __bf16 bf16x8 __attribute__((ext_vector_type(8)));
typedef float  f32x4  __attribute__((ext_vector_type(4)));

static constexpr int Mdim = 2048;   // B*S
static constexpr int Ndim = 4096;   // O
static constexpr int Kdim = 4096;   // I = G*A
static constexpr int DQ_BLOCKS = (Ndim * Kdim / 8) / 256;        // 8192
static constexpr int CVT_BLOCKS = (Mdim * Kdim / 8) / 256;       // 4096

// ---------------- fused prep: dequant W -> bf16 [O][K], cast X -> bf16 [M][K]
__global__ __launch_bounds__(256)
void prep(const float* __restrict__ binary, const float* __restrict__ alpha,
          const float* __restrict__ x, __bf16* __restrict__ w,
          __bf16* __restrict__ xb) {
  const int b = blockIdx.x;
  if (b < DQ_BLOCKS) {
    long e = ((long)b * 256 + threadIdx.x) * 8;       // 8 weights/thread
    int o = (int)(e >> 12);
    int g = (int)((e & 4095) >> 7);
    const float* al = alpha + ((long)o * 32 + g) * 3;
    float a0 = al[0], a1 = al[1], a2 = al[2];
    const float4* q = (const float4*)(binary + e * 3);  // 96B
    float4 q0 = q[0], q1 = q[1], q2 = q[2], q3 = q[3], q4 = q[4], q5 = q[5];
    bf16x8 wv;
    wv[0] = (__bf16)(a0 * q0.x + a1 * q0.y + a2 * q0.z);
    wv[1] = (__bf16)(a0 * q0.w + a1 * q1.x + a2 * q1.y);
    wv[2] = (__bf16)(a0 * q1.z + a1 * q1.w + a2 * q2.x);
    wv[3] = (__bf16)(a0 * q2.y + a1 * q2.z + a2 * q2.w);
    wv[4] = (__bf16)(a0 * q3.x + a1 * q3.y + a2 * q3.z);
    wv[5] = (__bf16)(a0 * q3.w + a1 * q4.x + a2 * q4.y);
    wv[6] = (__bf16)(a0 * q4.z + a1 * q4.w + a2 * q5.x);
    wv[7] = (__bf16)(a0 * q5.y + a1 * q5.z + a2 * q5.w);
    *(bf16x8*)(w + e) = wv;
  } else {
    long e = ((long)(b - DQ_BLOCKS) * 256 + threadIdx.x) * 8;
    float4 v0 = *(const float4*)(x + e);
    float4 v1 = *(const float4*)(x + e + 4);
    bf16x8 r;
    r[0] = (__bf16)v0.x; r[1] = (__bf16)v0.y; r[2] = (__bf16)v0.z; r[3] = (__bf16)v0.w;
    r[4] = (__bf16)v1.x; r[5] = (__bf16)v1.y; r[6] = (__bf16)v1.z; r[7] = (__bf16)v1.w;
    *(bf16x8*)(xb + e) = r;
  }
}

// ---------------- 128x256-tile bf16 GEMM, K=4096, triple-buffered LDS,
// counted vmcnt(6).  C[m][n] = sum_k A[m][k]*Bw[n][k] + bias[n]
static constexpr int NT = Kdim / 64;     // 64 K-tiles
static constexpr int BUF = 49152;        // 16KB A + 32KB B per buffer

__device__ __forceinline__ void g2l16(const void* g, void* l) {
  __builtin_amdgcn_global_load_lds(
      (const __attribute__((address_space(1))) void*)g,
      (__attribute__((address_space(3))) void*)l, 16, 0, 0);
}

#define BAR()    __builtin_amdgcn_s_barrier()
#define LGKM0()  asm volatile("s_waitcnt lgkmcnt(0)" ::: "memory")
#define SCHED0() __builtin_amdgcn_sched_barrier(0)
#define VMC6()   asm volatile("s_waitcnt vmcnt(6)" ::: "memory")
#define VMC0()   asm volatile("s_waitcnt vmcnt(0)" ::: "memory")

// stage: LDS linear dest; global source pre-swizzled (granule ^= row&7). [rule 21]
#define STAGE_A(t, bo) do { \
  _Pragma("unroll") for (int j_ = 0; j_ < 2; ++j_) \
    g2l16(baseA[j_] + (t) * 64, sm + (bo) + (w * 2 + j_) * 1024); \
} while (0)
#define STAGE_B(t, bo) do { \
  _Pragma("unroll") for (int j_ = 0; j_ < 4; ++j_) \
    g2l16(baseB[j_] + (t) * 64, sm + (bo) + 16384 + (w * 4 + j_) * 1024); \
} while (0)

#define LOAD_A4(dst, bo) do { \
  _Pragma("unroll") for (int m_ = 0; m_ < 4; ++m_) \
    _Pragma("unroll") for (int h_ = 0; h_ < 2; ++h_) \
      dst[m_][h_] = *(const bf16x8*)(sm + (bo) + aoffbase + m_ * 2048 + swz[h_]); \
} while (0)
#define LOAD_B2(dst, bo, n0_) do { \
  _Pragma("unroll") for (int n_ = 0; n_ < 2; ++n_) \
    _Pragma("unroll") for (int h_ = 0; h_ < 2; ++h_) \
      dst[n_][h_] = *(const bf16x8*)(sm + (bo) + boffbase + ((n0_) + n_) * 2048 + swz[h_]); \
} while (0)

#define MMA16(fa_, fb_, n0_) do { \
  __builtin_amdgcn_s_setprio(1); \
  _Pragma("unroll") for (int m_ = 0; m_ < 4; ++m_) \
    _Pragma("unroll") for (int n_ = 0; n_ < 2; ++n_) { \
      acc[m_][(n0_) + n_] = __builtin_amdgcn_mfma_f32_16x16x32_bf16( \
          fa_[m_][0], fb_[n_][0], acc[m_][(n0_) + n_], 0, 0, 0); \
      acc[m_][(n0_) + n_] = __builtin_amdgcn_mfma_f32_16x16x32_bf16( \
          fa_[m_][1], fb_[n_][1], acc[m_][(n0_) + n_], 0, 0, 0); \
    } \
  __builtin_amdgcn_s_setprio(0); \
} while (0)

__global__ __launch_bounds__(512, 2)
void gemm4(const __bf16* __restrict__ A, const __bf16* __restrict__ Bw,
           const float* __restrict__ bias, float* __restrict__ out) {
  __shared__ __align__(128) char sm[3 * BUF];   // 144 KB
  const int tid = threadIdx.x, lane = tid & 63, w = tid >> 6;
  const int wm = w >> 2, wn = w & 3;            // 2M x 4N waves; per-wave 64x64

  // XCD-aware bijective swizzle (256 blocks = 8 XCD x 32)
  const int bid = blockIdx.x;
  const int logical = (bid & 7) * 32 + (bid >> 3);
  const int tm = logical & 15;                  // 16 M-tiles (BM=128)
  const int tn = logical >> 4;                  // 16 N-tiles (BN=256)

  // staging per-lane source bases (pre-swizzled granule)
  const int rlo = lane >> 3;
  const int gsw = (lane & 7) ^ rlo;
  const __bf16* baseA[2];
  const __bf16* baseB[4];
#pragma unroll
  for (int j = 0; j < 2; ++j)
    baseA[j] = A + (long)(tm * 128 + w * 16 + j * 8 + rlo) * Kdim + gsw * 8;
#pragma unroll
  for (int j = 0; j < 4; ++j)
    baseB[j] = Bw + (long)(tn * 256 + w * 32 + j * 8 + rlo) * Kdim + gsw * 8;

  // read-side swizzled offsets
  int swz[2];
#pragma unroll
  for (int h = 0; h < 2; ++h)
    swz[h] = (((h * 4 + (lane >> 4)) ^ (lane & 7)) << 4);
  const int aoffbase = (wm * 64 + (lane & 15)) * 128;
  const int boffbase = 16384 + (wn * 64 + (lane & 15)) * 128;

  f32x4 acc[4][4] = {};

  // prologue: tile0 -> buf0, tile1 -> buf1; wait tile0, keep tile1's 6 in flight
  STAGE_A(0, 0);   STAGE_B(0, 0);
  STAGE_A(1, BUF); STAGE_B(1, BUF);
  VMC6();
  BAR();

  bf16x8 fa[4][2], fb01[2][2], fb23[2][2];
  int ba = 0, bb = BUF, bc = 2 * BUF;

  for (int t = 0; t < NT; ++t) {
    const bool pf = (t + 2 < NT);
    // P1: read A m0-3 + B n0-1; stage A(t+2)
    LOAD_A4(fa, ba);
    LOAD_B2(fb01, ba, 0);
    if (pf) STAGE_A(t + 2, bc);
    BAR(); LGKM0(); SCHED0();
    MMA16(fa, fb01, 0);
    BAR();
    // P2: read B n2-3; stage B(t+2); counted wait -> tile t+1 resident
    LOAD_B2(fb23, ba, 2);
    if (pf) STAGE_B(t + 2, bc);
    if (t < NT - 2) { VMC6(); } else { VMC0(); }
    BAR(); LGKM0(); SCHED0();
    MMA16(fa, fb23, 2);
    BAR();
    int tmp = ba; ba = bb; bb = bc; bc = tmp;
  }

  // ---- epilogue: acc -> LDS [128][260] f32 (pad kills write conflicts),
  //      then coalesced float4 row stores with fused bias.
  float* lf = (float*)sm;                       // 128*260*4 = 133120 <= 147456
  const int r4 = (lane >> 4) * 4;
  const int cl = lane & 15;
#pragma unroll
  for (int m = 0; m < 4; ++m)
#pragma unroll
    for (int n = 0; n < 4; ++n)
#pragma unroll
      for (int r = 0; r < 4; ++r) {
        int row = wm * 64 + m * 16 + r4 + r;
        int col = wn * 64 + n * 16 + cl;
        lf[row * 260 + col] = acc[m][n][r];
      }
  __syncthreads();
#pragma unroll
  for (int i = 0; i < 16; ++i) {
    int idx = tid + i * 512;                    // 8192 float4 chunks
    int row = idx >> 6;                         // 64 chunks per 256-col row
    int c4 = idx & 63;
    f32x4 v = *(const f32x4*)(lf + row * 260 + c4 * 4);
    float4 bv = *(const float4*)(bias + tn * 256 + c4 * 4);
    v[0] += bv.x; v[1] += bv.y; v[2] += bv.z; v[3] += bv.w;
    *(f32x4*)(out + (long)(tm * 128 + row) * Ndim + tn * 256 + c4 * 4) = v;
  }
}

extern "C" void kernel_launch(void* const* d_in, const int* in_sizes, int n_in,
                              void* d_out, int out_size, void* d_ws, size_t ws_size,
                              hipStream_t stream) {
  const float* x      = (const float*)d_in[0];
  const float* binary = (const float*)d_in[1];
  const float* alpha  = (const float*)d_in[2];
  const float* bias   = (const float*)d_in[3];
  float* out = (float*)d_out;

  __bf16* wb = (__bf16*)d_ws;                              // 32 MB  W bf16 [N][K]
  __bf16* xb = wb + (size_t)Ndim * Kdim;                   // 16 MB  X bf16 [M][K]

  prep<<<dim3(DQ_BLOCKS + CVT_BLOCKS), 256, 0, stream>>>(binary, alpha, x, wb, xb);
  gemm4<<<dim3(256), 512, 0, stream>>>(xb, wb, bias, out);
}